// Round 6
// baseline (60.159 us; speedup 1.0000x reference)
//
#include <hip/hip_runtime.h>
#include <math.h>

#define B_    32
#define NB_   1024
#define H_    768
#define K_    384
#define C_    64
#define ROWS_ 32                 // rows per gate block
#define NSTEP_ 24                // 24 K-steps of 32

typedef __attribute__((ext_vector_type(8))) short bf16x8;
typedef __attribute__((ext_vector_type(4))) float f32x4;

__device__ __forceinline__ short f2bf(float f) {   // RNE fp32 -> bf16 bits
    unsigned u = __float_as_uint(f);
    unsigned r = (u + 0x7fffu + ((u >> 16) & 1u)) >> 16;
    return (short)r;
}
__device__ __forceinline__ float ftanh(float x) {  // tanh = 1 - 2/(e^2x+1)
    float e = __expf(2.f * x);
    return 1.f - 2.f * __builtin_amdgcn_rcpf(e + 1.f);
}

// ---------------------------------------------------------------------------
// W1 (768x384 fp32) -> bf16 swizzled to exact MFMA B-fragment order.
// frag (s,t): lane l, elem i = W1[s*32+(l>>4)*8+i][t*16+(l&15)]
// ---------------------------------------------------------------------------
__global__ __launch_bounds__(256) void prep_w1(const float* __restrict__ W1,
                                               short* __restrict__ swz)
{
    int idx = blockIdx.x * 256 + threadIdx.x;
    int k = idx / K_, n = idx % K_;
    float v = W1[idx];
    int s = k >> 5, g = (k >> 3) & 3, i = k & 7;
    int t = n >> 4, nn = n & 15;
    swz[((s * 24 + t) * 512) + (g * 16 + nn) * 8 + i] = f2bf(v);
}

// ---------------------------------------------------------------------------
// Per-batch compaction of active rows. 1 block per b, 1024 threads.
// list[b*NB+i] = n for i < cnt[b]; tail filled with 0 (benign duplicates).
// ---------------------------------------------------------------------------
__global__ __launch_bounds__(1024) void compact_kernel(
    const int* __restrict__ active, int* __restrict__ list, int* __restrict__ cnt)
{
    __shared__ int wsum[16];
    __shared__ int wbase[17];
    const int b = blockIdx.x, tid = threadIdx.x, lane = tid & 63, wid = tid >> 6;
    const int flag = active[b * NB_ + tid] != 0;
    const unsigned long long m = __ballot(flag);
    if (lane == 0) wsum[wid] = __popcll(m);
    __syncthreads();
    if (tid == 0) {
        int r = 0;
        for (int i = 0; i < 16; ++i) { wbase[i] = r; r += wsum[i]; }
        wbase[16] = r;
        cnt[b] = r;
    }
    __syncthreads();
    const int total = wbase[16];
    if (flag) {
        const int pos = wbase[wid] + __popcll(m & ((1ull << lane) - 1ull));
        list[b * NB_ + pos] = tid;
    }
    if (tid >= total) list[b * NB_ + tid] = 0;
}

// ---------------------------------------------------------------------------
// Gate MLP via MFMA over compacted active rows.
// Block: 256 thr (4 waves) = 32 list-rows x 384 cols; wave w: cols [w*96,+96)
// = 6 B-frags read directly from pre-swizzled global (L2), 1-step prefetch.
// A: fp32 global (1 float4/thr/step, 2-step prefetch) -> bf16 LDS dbuf,
// XOR-swizzled. Raw s_barrier + counted waits keep loads in flight.
// Grid = B*32 blocks; ~half early-exit; expected ~2-3 active blocks/CU (TLP).
// ---------------------------------------------------------------------------
__global__ __launch_bounds__(256, 3) void gate_kernel(
    const float* __restrict__ tokens, const short* __restrict__ swz,
    const float* __restrict__ b1, const float* __restrict__ W2,
    const float* __restrict__ b2, const int* __restrict__ list,
    const int* __restrict__ cnt, float* __restrict__ gate)
{
    __shared__ __align__(16) short As[2][1024];   // 2 x 2 KiB bf16 (32x32)
    __shared__ float red[4][32];

    const int b = blockIdx.x >> 5;
    const int chunk = blockIdx.x & 31;
    if (chunk * ROWS_ >= cnt[b]) return;          // uniform early-exit

    const int tid = threadIdx.x;
    const int lane = tid & 63;
    const int w = tid >> 6;                       // wave 0..3

    // --- A staging geometry: thread -> (row r, 4-float chunk c8)
    const int r   = tid >> 3;                     // 0..31 local row
    const int c8  = tid & 7;                      // k-chunk of 4 floats
    const int g2w = c8 >> 1, hw = c8 & 1;
    const int fw  = r >> 4,  roww = r & 15;
    const int woff = ((fw * 4 + g2w) * 16 + (roww ^ (g2w << 1))) * 8 + hw * 4;
    const int nrow = list[b * NB_ + chunk * ROWS_ + r];
    const float* aptr = tokens + ((size_t)b * NB_ + nrow) * H_ + c8 * 4;

    // --- A fragment read geometry (lane -> 8 bf16)
    const int g2r  = lane >> 4;
    const int rowr = (lane & 15) ^ (g2r << 1);
    const int roff0 = ((0 + g2r) * 16 + rowr) * 8;
    const int roff1 = ((4 + g2r) * 16 + rowr) * 8;

    const short* bbase = swz + (w * 6) * 512 + lane * 8;

    f32x4 acc[6][2];
#pragma unroll
    for (int j = 0; j < 6; ++j)
#pragma unroll
        for (int f = 0; f < 2; ++f) acc[j][f] = (f32x4){0.f, 0.f, 0.f, 0.f};

    // ---- prologue: A[0]->pe, A[1]->po, B[0]->be*; write step-0 LDS
    float4 pe = *(const float4*)(aptr);
    float4 po = *(const float4*)(aptr + 32);
    bf16x8 be0 = *(const bf16x8*)(bbase);
    bf16x8 be1 = *(const bf16x8*)(bbase + 512);
    bf16x8 be2 = *(const bf16x8*)(bbase + 1024);
    bf16x8 be3 = *(const bf16x8*)(bbase + 1536);
    bf16x8 be4 = *(const bf16x8*)(bbase + 2048);
    bf16x8 be5 = *(const bf16x8*)(bbase + 2560);
    bf16x8 bo0 = be0, bo1 = be1, bo2 = be2, bo3 = be3, bo4 = be4, bo5 = be5;
    {
        short4 av = {f2bf(pe.x), f2bf(pe.y), f2bf(pe.z), f2bf(pe.w)};
        *(short4*)&As[0][woff] = av;
    }
    asm volatile("s_waitcnt lgkmcnt(0)" ::: "memory");
    __builtin_amdgcn_s_barrier();
    __builtin_amdgcn_sched_barrier(0);

#define MFMA_STEP(BUF, B0, B1, B2, B3, B4, B5)                                \
    do {                                                                      \
        bf16x8 a0 = *(const bf16x8*)&As[BUF][roff0];                          \
        bf16x8 a1 = *(const bf16x8*)&As[BUF][roff1];                          \
        acc[0][0] = __builtin_amdgcn_mfma_f32_16x16x32_bf16(a0, B0, acc[0][0], 0, 0, 0); \
        acc[0][1] = __builtin_amdgcn_mfma_f32_16x16x32_bf16(a1, B0, acc[0][1], 0, 0, 0); \
        acc[1][0] = __builtin_amdgcn_mfma_f32_16x16x32_bf16(a0, B1, acc[1][0], 0, 0, 0); \
        acc[1][1] = __builtin_amdgcn_mfma_f32_16x16x32_bf16(a1, B1, acc[1][1], 0, 0, 0); \
        acc[2][0] = __builtin_amdgcn_mfma_f32_16x16x32_bf16(a0, B2, acc[2][0], 0, 0, 0); \
        acc[2][1] = __builtin_amdgcn_mfma_f32_16x16x32_bf16(a1, B2, acc[2][1], 0, 0, 0); \
        acc[3][0] = __builtin_amdgcn_mfma_f32_16x16x32_bf16(a0, B3, acc[3][0], 0, 0, 0); \
        acc[3][1] = __builtin_amdgcn_mfma_f32_16x16x32_bf16(a1, B3, acc[3][1], 0, 0, 0); \
        acc[4][0] = __builtin_amdgcn_mfma_f32_16x16x32_bf16(a0, B4, acc[4][0], 0, 0, 0); \
        acc[4][1] = __builtin_amdgcn_mfma_f32_16x16x32_bf16(a1, B4, acc[4][1], 0, 0, 0); \
        acc[5][0] = __builtin_amdgcn_mfma_f32_16x16x32_bf16(a0, B5, acc[5][0], 0, 0, 0); \
        acc[5][1] = __builtin_amdgcn_mfma_f32_16x16x32_bf16(a1, B5, acc[5][1], 0, 0, 0); \
    } while (0)

    for (int s = 0; s < NSTEP_; s += 2) {
        // ---- even half-step: compute step s (buf0, be*)
        if (s + 2 < NSTEP_) pe = *(const float4*)(aptr + (s + 2) * 32);
        if (s + 1 < NSTEP_) {
            const short* bp = bbase + (s + 1) * 12288;
            bo0 = *(const bf16x8*)(bp);
            bo1 = *(const bf16x8*)(bp + 512);
            bo2 = *(const bf16x8*)(bp + 1024);
            bo3 = *(const bf16x8*)(bp + 1536);
            bo4 = *(const bf16x8*)(bp + 2048);
            bo5 = *(const bf16x8*)(bp + 2560);
        }
        MFMA_STEP(0, be0, be1, be2, be3, be4, be5);
        if (s + 1 < NSTEP_) {
            short4 av = {f2bf(po.x), f2bf(po.y), f2bf(po.z), f2bf(po.w)};
            *(short4*)&As[1][woff] = av;
        }
        asm volatile("s_waitcnt lgkmcnt(0)" ::: "memory");
        __builtin_amdgcn_s_barrier();
        __builtin_amdgcn_sched_barrier(0);

        // ---- odd half-step: compute step s+1 (buf1, bo*)
        if (s + 3 < NSTEP_) po = *(const float4*)(aptr + (s + 3) * 32);
        if (s + 2 < NSTEP_) {
            const short* bp = bbase + (s + 2) * 12288;
            be0 = *(const bf16x8*)(bp);
            be1 = *(const bf16x8*)(bp + 512);
            be2 = *(const bf16x8*)(bp + 1024);
            be3 = *(const bf16x8*)(bp + 1536);
            be4 = *(const bf16x8*)(bp + 2048);
            be5 = *(const bf16x8*)(bp + 2560);
        }
        MFMA_STEP(1, bo0, bo1, bo2, bo3, bo4, bo5);
        if (s + 2 < NSTEP_) {
            short4 av = {f2bf(pe.x), f2bf(pe.y), f2bf(pe.z), f2bf(pe.w)};
            *(short4*)&As[0][woff] = av;
        }
        asm volatile("s_waitcnt lgkmcnt(0)" ::: "memory");
        __builtin_amdgcn_s_barrier();
        __builtin_amdgcn_sched_barrier(0);
    }
#undef MFMA_STEP

    // ---- epilogue: gate[row] = b2 + sum_n tanh(h + b1[n]) * W2[n]
    float ps[2][4];
#pragma unroll
    for (int f = 0; f < 2; ++f)
#pragma unroll
        for (int rr = 0; rr < 4; ++rr) ps[f][rr] = 0.f;

#pragma unroll
    for (int j = 0; j < 6; ++j) {
        const int n = (w * 6 + j) * 16 + (lane & 15);
        const float bb = b1[n];
        const float ww = W2[n];
#pragma unroll
        for (int f = 0; f < 2; ++f)
#pragma unroll
            for (int rr = 0; rr < 4; ++rr)
                ps[f][rr] += ftanh(acc[j][f][rr] + bb) * ww;
    }
#pragma unroll
    for (int m = 1; m < 16; m <<= 1)
#pragma unroll
        for (int f = 0; f < 2; ++f)
#pragma unroll
            for (int rr = 0; rr < 4; ++rr)
                ps[f][rr] += __shfl_xor(ps[f][rr], m, 64);

    if ((lane & 15) == 0) {
        const int rbase = (lane >> 4) * 4;
#pragma unroll
        for (int f = 0; f < 2; ++f)
#pragma unroll
            for (int rr = 0; rr < 4; ++rr)
                red[w][f * 16 + rbase + rr] = ps[f][rr];
    }
    __syncthreads();
    if (tid < ROWS_) {
        float sg = b2[0];
#pragma unroll
        for (int q = 0; q < 4; ++q) sg += red[q][tid];
        gate[b * NB_ + list[b * NB_ + chunk * ROWS_ + tid]] = sg;
    }
}

// ---------------------------------------------------------------------------
// Per-(b,c) masked softmax + weighted token sum; compacted phase C, float4.
// ---------------------------------------------------------------------------
__global__ __launch_bounds__(256) void agg_kernel(
    const float* __restrict__ tokens, const int* __restrict__ active,
    const int* __restrict__ cmap, const float* __restrict__ gate,
    float* __restrict__ out_tok, float* __restrict__ out_act)
{
    __shared__ float wls[NB_];
    __shared__ float red[256];
    __shared__ int   idxs[NB_];
    __shared__ float wts[NB_];
    __shared__ int   gbase[17];

    const int b = blockIdx.x >> 6, c = blockIdx.x & 63;
    const int tid = threadIdx.x, lane = tid & 63, wid = tid >> 6;

    float lmax = -INFINITY;
    for (int n = tid; n < NB_; n += 256) {
        const bool msk = (active[b * NB_ + n] != 0) && (cmap[n] == c);
        const float g  = msk ? gate[b * NB_ + n] : -INFINITY;
        wls[n] = g;
        lmax = fmaxf(lmax, g);
    }
    red[tid] = lmax; __syncthreads();
    for (int s = 128; s > 0; s >>= 1) {
        if (tid < s) red[tid] = fmaxf(red[tid], red[tid + s]);
        __syncthreads();
    }
    const float m = red[0]; __syncthreads();
    const float msafe = (m > -INFINITY) ? m : 0.f;

    float lsum = 0.f;
    for (int n = tid; n < NB_; n += 256) {
        const float g = wls[n];
        const float e = (g > -INFINITY) ? __expf(g - msafe) : 0.f;
        wls[n] = e; lsum += e;
    }
    red[tid] = lsum; __syncthreads();
    for (int s = 128; s > 0; s >>= 1) {
        if (tid < s) red[tid] += red[tid + s];
        __syncthreads();
    }
    const float ssum = red[0];
    const float inv  = (ssum > 0.f) ? 1.f / ssum : 0.f;
    __syncthreads();

#pragma unroll
    for (int it = 0; it < 4; ++it) {
        const int n = it * 256 + wid * 64 + lane;
        const unsigned long long mask = __ballot(wls[n] > 0.f);
        if (lane == 0) gbase[1 + it * 4 + wid] = __popcll(mask);
    }
    __syncthreads();
    if (tid == 0) {
        gbase[0] = 0;
        for (int i = 1; i <= 16; ++i) gbase[i] += gbase[i - 1];
    }
    __syncthreads();
#pragma unroll
    for (int it = 0; it < 4; ++it) {
        const int n = it * 256 + wid * 64 + lane;
        const float e = wls[n];
        const unsigned long long mask = __ballot(e > 0.f);
        if (e > 0.f) {
            const int pos = gbase[it * 4 + wid] +
                            __popcll(mask & ((1ull << lane) - 1ull));
            idxs[pos] = n;
            wts[pos]  = e * inv;
        }
    }
    __syncthreads();
    const int cnt = gbase[16];

    // phase C: weighted accumulation, float4 (192 lanes x 16 B per row)
    if (tid < 192) {
        const int d = tid * 4;
        const float* tb = tokens + (size_t)b * NB_ * H_ + d;
        float4 a = {0.f, 0.f, 0.f, 0.f};
        for (int i = 0; i < cnt; ++i) {
            const float wv = wts[i];
            const float4 v = *(const float4*)(tb + (size_t)idxs[i] * H_);
            a.x += wv * v.x; a.y += wv * v.y;
            a.z += wv * v.z; a.w += wv * v.w;
        }
        *(float4*)(out_tok + ((size_t)(b * C_ + c)) * H_ + d) = a;
    }
    if (tid == 0) out_act[b * C_ + c] = (m > -INFINITY) ? 1.f : 0.f;
}

// ---------------------------------------------------------------------------
extern "C" void kernel_launch(void* const* d_in, const int* in_sizes, int n_in,
                              void* d_out, int out_size, void* d_ws, size_t ws_size,
                              hipStream_t stream)
{
    const float* tokens = (const float*)d_in[0];
    const int*   active = (const int*)  d_in[1];
    const int*   cmap   = (const int*)  d_in[2];
    const float* W1     = (const float*)d_in[3];
    const float* b1     = (const float*)d_in[4];
    const float* W2     = (const float*)d_in[5];
    const float* b2     = (const float*)d_in[6];

    float* out      = (float*)d_out;
    float* out_act  = out + (size_t)B_ * C_ * H_;

    short* swz     = (short*)d_ws;                          // 589824 B
    float* gate_ws = (float*)((char*)d_ws + 589824);        // 131072 B
    int*   list    = (int*)  ((char*)d_ws + 720896);        // 131072 B
    int*   cntb    = (int*)  ((char*)d_ws + 851968);        // 128 B

    compact_kernel<<<B_, 1024, 0, stream>>>(active, list, cntb);
    prep_w1<<<(H_ * K_) / 256, 256, 0, stream>>>(W1, swz);
    gate_kernel<<<B_ * 32, 256, 0, stream>>>(tokens, swz, b1, W2, b2, list, cntb, gate_ws);
    agg_kernel<<<B_ * C_, 256, 0, stream>>>(tokens, active, cmap, gate_ws, out, out_act);
}

// Round 7
// 57.538 us; speedup vs baseline: 1.0456x; 1.0456x over previous
//
#include <hip/hip_runtime.h>
#include <math.h>

#define B_    32
#define NB_   1024
#define H_    768
#define K_    384
#define C_    64
#define ROWS_ 32                 // rows per gate block
#define NSTEP_ 24                // 24 K-steps of 32

typedef __attribute__((ext_vector_type(8))) short bf16x8;
typedef __attribute__((ext_vector_type(4))) float f32x4;

__device__ __forceinline__ short f2bf(float f) {   // RNE fp32 -> bf16 bits
    unsigned u = __float_as_uint(f);
    unsigned r = (u + 0x7fffu + ((u >> 16) & 1u)) >> 16;
    return (short)r;
}
__device__ __forceinline__ float ftanh(float x) {  // tanh = 1 - 2/(e^2x+1)
    float e = __expf(2.f * x);
    return 1.f - 2.f * __builtin_amdgcn_rcpf(e + 1.f);
}

// ---------------------------------------------------------------------------
// W1 (768x384 fp32) -> bf16 swizzled to exact MFMA B-fragment order.
// frag (s,t): lane l, elem i = W1[s*32+(l>>4)*8+i][t*16+(l&15)]
// ---------------------------------------------------------------------------
__global__ __launch_bounds__(256) void prep_w1(const float* __restrict__ W1,
                                               short* __restrict__ swz)
{
    int idx = blockIdx.x * 256 + threadIdx.x;
    int k = idx / K_, n = idx % K_;
    float v = W1[idx];
    int s = k >> 5, g = (k >> 3) & 3, i = k & 7;
    int t = n >> 4, nn = n & 15;
    swz[((s * 24 + t) * 512) + (g * 16 + nn) * 8 + i] = f2bf(v);
}

// ---------------------------------------------------------------------------
// Per-batch compaction of active rows. 1 block per b, 1024 threads.
// ---------------------------------------------------------------------------
__global__ __launch_bounds__(1024) void compact_kernel(
    const int* __restrict__ active, int* __restrict__ list, int* __restrict__ cnt)
{
    __shared__ int wsum[16];
    __shared__ int wbase[17];
    const int b = blockIdx.x, tid = threadIdx.x, lane = tid & 63, wid = tid >> 6;
    const int flag = active[b * NB_ + tid] != 0;
    const unsigned long long m = __ballot(flag);
    if (lane == 0) wsum[wid] = __popcll(m);
    __syncthreads();
    if (tid == 0) {
        int r = 0;
        for (int i = 0; i < 16; ++i) { wbase[i] = r; r += wsum[i]; }
        wbase[16] = r;
        cnt[b] = r;
    }
    __syncthreads();
    const int total = wbase[16];
    if (flag) {
        const int pos = wbase[wid] + __popcll(m & ((1ull << lane) - 1ull));
        list[b * NB_ + pos] = tid;
    }
    if (tid >= total) list[b * NB_ + tid] = 0;
}

// ---------------------------------------------------------------------------
// Gate MLP via MFMA over compacted active rows.
// Block: 256 thr (4 waves) = 32 rows x 384 cols; wave w: cols [w*96,+96).
// Deep register pipeline, fully unrolled k-loop (compile-time ring indices):
//   step s: load A[s+4] (pa ring of 4 -> 3-step HBM cover),
//           load B[s+2] (bs ring of 3 -> 2-step L2 cover),
//           MFMA on LDS buf[s&1] x bs[s%3],
//           cvt+ds_write A[s+1] -> buf[(s+1)&1],
//           lgkmcnt(0); s_barrier  (vmem never drained at barrier).
// ---------------------------------------------------------------------------
__global__ __launch_bounds__(256, 2) void gate_kernel(
    const float* __restrict__ tokens, const short* __restrict__ swz,
    const float* __restrict__ b1, const float* __restrict__ W2,
    const float* __restrict__ b2, const int* __restrict__ list,
    const int* __restrict__ cnt, float* __restrict__ gate)
{
    __shared__ __align__(16) short As[2][1024];   // 2 x 2 KiB bf16 (32x32)
    __shared__ float red[4][32];

    const int b = blockIdx.x >> 5;
    const int chunk = blockIdx.x & 31;
    if (chunk * ROWS_ >= cnt[b]) return;          // uniform early-exit

    const int tid = threadIdx.x;
    const int lane = tid & 63;
    const int w = tid >> 6;                       // wave 0..3

    // --- A staging geometry: thread -> (row r, 4-float chunk c8)
    const int r   = tid >> 3;                     // 0..31 local row
    const int c8  = tid & 7;                      // k-chunk of 4 floats
    const int g2w = c8 >> 1, hw = c8 & 1;
    const int fw  = r >> 4,  roww = r & 15;
    const int woff = ((fw * 4 + g2w) * 16 + (roww ^ (g2w << 1))) * 8 + hw * 4;
    const int nrow = list[b * NB_ + chunk * ROWS_ + r];
    const float* aptr = tokens + ((size_t)b * NB_ + nrow) * H_ + c8 * 4;

    // --- A fragment read geometry (lane -> 8 bf16)
    const int g2r  = lane >> 4;
    const int rowr = (lane & 15) ^ (g2r << 1);
    const int roff0 = ((0 + g2r) * 16 + rowr) * 8;
    const int roff1 = ((4 + g2r) * 16 + rowr) * 8;

    const short* bbase = swz + (w * 6) * 512 + lane * 8;

    f32x4 acc[6][2];
#pragma unroll
    for (int j = 0; j < 6; ++j)
#pragma unroll
        for (int f = 0; f < 2; ++f) acc[j][f] = (f32x4){0.f, 0.f, 0.f, 0.f};

    float4 pa[4];
    bf16x8 bs[3][6];

    // ---- prologue: A[0..3] -> pa, B[0]->bs[0], B[1]->bs[1]; write step-0 LDS
    pa[0] = *(const float4*)(aptr + 0 * 32);
    pa[1] = *(const float4*)(aptr + 1 * 32);
    pa[2] = *(const float4*)(aptr + 2 * 32);
    pa[3] = *(const float4*)(aptr + 3 * 32);
#pragma unroll
    for (int j = 0; j < 6; ++j)
        bs[0][j] = *(const bf16x8*)(bbase + 0 * 12288 + j * 512);
#pragma unroll
    for (int j = 0; j < 6; ++j)
        bs[1][j] = *(const bf16x8*)(bbase + 1 * 12288 + j * 512);
    {
        short4 av = {f2bf(pa[0].x), f2bf(pa[0].y), f2bf(pa[0].z), f2bf(pa[0].w)};
        *(short4*)&As[0][woff] = av;
    }
    asm volatile("s_waitcnt lgkmcnt(0)" ::: "memory");
    __builtin_amdgcn_s_barrier();
    __builtin_amdgcn_sched_barrier(0);

#pragma unroll
    for (int s = 0; s < NSTEP_; ++s) {
        // deep prefetches (compile-time ring slots; waits are counted vmcnt)
        if (s + 4 < NSTEP_)
            pa[(s + 4) & 3] = *(const float4*)(aptr + (s + 4) * 32);
        if (s + 2 < NSTEP_) {
            const short* bp = bbase + (size_t)(s + 2) * 12288;
#pragma unroll
            for (int j = 0; j < 6; ++j)
                bs[(s + 2) % 3][j] = *(const bf16x8*)(bp + j * 512);
        }
        // compute step s
        {
            bf16x8 a0 = *(const bf16x8*)&As[s & 1][roff0];
            bf16x8 a1 = *(const bf16x8*)&As[s & 1][roff1];
#pragma unroll
            for (int j = 0; j < 6; ++j) {
                acc[j][0] = __builtin_amdgcn_mfma_f32_16x16x32_bf16(
                                a0, bs[s % 3][j], acc[j][0], 0, 0, 0);
                acc[j][1] = __builtin_amdgcn_mfma_f32_16x16x32_bf16(
                                a1, bs[s % 3][j], acc[j][1], 0, 0, 0);
            }
        }
        // stage A[s+1] into the other LDS buffer (loaded 3 steps ago)
        if (s + 1 < NSTEP_) {
            float4 q = pa[(s + 1) & 3];
            short4 av = {f2bf(q.x), f2bf(q.y), f2bf(q.z), f2bf(q.w)};
            *(short4*)&As[(s + 1) & 1][woff] = av;
        }
        asm volatile("s_waitcnt lgkmcnt(0)" ::: "memory");
        __builtin_amdgcn_s_barrier();
        __builtin_amdgcn_sched_barrier(0);
    }

    // ---- epilogue: gate[row] = b2 + sum_n tanh(h + b1[n]) * W2[n]
    float ps[2][4];
#pragma unroll
    for (int f = 0; f < 2; ++f)
#pragma unroll
        for (int rr = 0; rr < 4; ++rr) ps[f][rr] = 0.f;

#pragma unroll
    for (int j = 0; j < 6; ++j) {
        const int n = (w * 6 + j) * 16 + (lane & 15);
        const float bb = b1[n];
        const float ww = W2[n];
#pragma unroll
        for (int f = 0; f < 2; ++f)
#pragma unroll
            for (int rr = 0; rr < 4; ++rr)
                ps[f][rr] += ftanh(acc[j][f][rr] + bb) * ww;
    }
#pragma unroll
    for (int m = 1; m < 16; m <<= 1)
#pragma unroll
        for (int f = 0; f < 2; ++f)
#pragma unroll
            for (int rr = 0; rr < 4; ++rr)
                ps[f][rr] += __shfl_xor(ps[f][rr], m, 64);

    if ((lane & 15) == 0) {
        const int rbase = (lane >> 4) * 4;
#pragma unroll
        for (int f = 0; f < 2; ++f)
#pragma unroll
            for (int rr = 0; rr < 4; ++rr)
                red[w][f * 16 + rbase + rr] = ps[f][rr];
    }
    __syncthreads();
    if (tid < ROWS_) {
        float sg = b2[0];
#pragma unroll
        for (int q = 0; q < 4; ++q) sg += red[q][tid];
        gate[b * NB_ + list[b * NB_ + chunk * ROWS_ + tid]] = sg;
    }
}

// ---------------------------------------------------------------------------
// Per-(b,c) masked softmax + weighted token sum; compacted phase C, float4.
// ---------------------------------------------------------------------------
__global__ __launch_bounds__(256) void agg_kernel(
    const float* __restrict__ tokens, const int* __restrict__ active,
    const int* __restrict__ cmap, const float* __restrict__ gate,
    float* __restrict__ out_tok, float* __restrict__ out_act)
{
    __shared__ float wls[NB_];
    __shared__ float red[256];
    __shared__ int   idxs[NB_];
    __shared__ float wts[NB_];
    __shared__ int   gbase[17];

    const int b = blockIdx.x >> 6, c = blockIdx.x & 63;
    const int tid = threadIdx.x, lane = tid & 63, wid = tid >> 6;

    float lmax = -INFINITY;
    for (int n = tid; n < NB_; n += 256) {
        const bool msk = (active[b * NB_ + n] != 0) && (cmap[n] == c);
        const float g  = msk ? gate[b * NB_ + n] : -INFINITY;
        wls[n] = g;
        lmax = fmaxf(lmax, g);
    }
    red[tid] = lmax; __syncthreads();
    for (int s = 128; s > 0; s >>= 1) {
        if (tid < s) red[tid] = fmaxf(red[tid], red[tid + s]);
        __syncthreads();
    }
    const float m = red[0]; __syncthreads();
    const float msafe = (m > -INFINITY) ? m : 0.f;

    float lsum = 0.f;
    for (int n = tid; n < NB_; n += 256) {
        const float g = wls[n];
        const float e = (g > -INFINITY) ? __expf(g - msafe) : 0.f;
        wls[n] = e; lsum += e;
    }
    red[tid] = lsum; __syncthreads();
    for (int s = 128; s > 0; s >>= 1) {
        if (tid < s) red[tid] += red[tid + s];
        __syncthreads();
    }
    const float ssum = red[0];
    const float inv  = (ssum > 0.f) ? 1.f / ssum : 0.f;
    __syncthreads();

#pragma unroll
    for (int it = 0; it < 4; ++it) {
        const int n = it * 256 + wid * 64 + lane;
        const unsigned long long mask = __ballot(wls[n] > 0.f);
        if (lane == 0) gbase[1 + it * 4 + wid] = __popcll(mask);
    }
    __syncthreads();
    if (tid == 0) {
        gbase[0] = 0;
        for (int i = 1; i <= 16; ++i) gbase[i] += gbase[i - 1];
    }
    __syncthreads();
#pragma unroll
    for (int it = 0; it < 4; ++it) {
        const int n = it * 256 + wid * 64 + lane;
        const float e = wls[n];
        const unsigned long long mask = __ballot(e > 0.f);
        if (e > 0.f) {
            const int pos = gbase[it * 4 + wid] +
                            __popcll(mask & ((1ull << lane) - 1ull));
            idxs[pos] = n;
            wts[pos]  = e * inv;
        }
    }
    __syncthreads();
    const int cnt = gbase[16];

    // phase C: weighted accumulation, float4 (192 lanes x 16 B per row)
    if (tid < 192) {
        const int d = tid * 4;
        const float* tb = tokens + (size_t)b * NB_ * H_ + d;
        float4 a = {0.f, 0.f, 0.f, 0.f};
        for (int i = 0; i < cnt; ++i) {
            const float wv = wts[i];
            const float4 v = *(const float4*)(tb + (size_t)idxs[i] * H_);
            a.x += wv * v.x; a.y += wv * v.y;
            a.z += wv * v.z; a.w += wv * v.w;
        }
        *(float4*)(out_tok + ((size_t)(b * C_ + c)) * H_ + d) = a;
    }
    if (tid == 0) out_act[b * C_ + c] = (m > -INFINITY) ? 1.f : 0.f;
}

// ---------------------------------------------------------------------------
extern "C" void kernel_launch(void* const* d_in, const int* in_sizes, int n_in,
                              void* d_out, int out_size, void* d_ws, size_t ws_size,
                              hipStream_t stream)
{
    const float* tokens = (const float*)d_in[0];
    const int*   active = (const int*)  d_in[1];
    const int*   cmap   = (const int*)  d_in[2];
    const float* W1     = (const float*)d_in[3];
    const float* b1     = (const float*)d_in[4];
    const float* W2     = (const float*)d_in[5];
    const float* b2     = (const float*)d_in[6];

    float* out      = (float*)d_out;
    float* out_act  = out + (size_t)B_ * C_ * H_;

    short* swz     = (short*)d_ws;                          // 589824 B
    float* gate_ws = (float*)((char*)d_ws + 589824);        // 131072 B
    int*   list    = (int*)  ((char*)d_ws + 720896);        // 131072 B
    int*   cntb    = (int*)  ((char*)d_ws + 851968);        // 128 B

    compact_kernel<<<B_, 1024, 0, stream>>>(active, list, cntb);
    prep_w1<<<(H_ * K_) / 256, 256, 0, stream>>>(W1, swz);
    gate_kernel<<<B_ * 32, 256, 0, stream>>>(tokens, swz, b1, W2, b2, list, cntb, gate_ws);
    agg_kernel<<<B_ * C_, 256, 0, stream>>>(tokens, active, cmap, gate_ws, out, out_act);
}